// Round 7
// baseline (21102.649 us; speedup 1.0000x reference)
//
#include <hip/hip_runtime.h>
#include <cstdint>
#include <cstddef>

typedef __attribute__((ext_vector_type(8))) short bf16x8;
typedef __attribute__((ext_vector_type(4))) float f32x4;
typedef uint16_t u16;
typedef uint32_t u32;
typedef uint64_t u64;

#define NS 4096

// ---------------- fixed workspace layout (bytes) ----------------
// WhS: restaged Wh fragments for kq=5,6,7 (lane-contiguous, coalesced) 192 KB
#define OFF_WHS    ((size_t)262144)                   // 192 KB (old hXM slot)
#define OFF_STATE  ((size_t)524288)                   // 128 KB: c then h, f32 [64][256]
#define OFF_WHT    ((size_t)655360)                   // 512 KB
#define OFF_WXTH   (OFF_WHT   + (size_t)524288)
#define OFF_WXTL   (OFF_WXTH  + (size_t)262144)
#define OFF_WEF1H  (OFF_WXTL  + (size_t)262144)
#define OFF_WEF1L  (OFF_WEF1H + (size_t)32768)
#define OFF_WEF3H  (OFF_WEF1L + (size_t)32768)
#define OFF_WEF3L  (OFF_WEF3H + (size_t)65536)
#define OFF_CH     ((size_t)2*1024*1024)              // chunk region
// per-step: s hi/lo + x hi/lo + e1 hi/lo (6x16KB) + xw f32 (256KB) + j f32 (64KB)
#define CH_BYTES_PER_SC ((size_t)425984)

// ---------------- helpers ----------------
static __device__ __forceinline__ float bf2f(u16 u){
  union { uint32_t i; float f; } v; v.i = ((uint32_t)u) << 16; return v.f;
}
static __device__ __forceinline__ u16 f2bf(float f){
  union { float f; uint32_t u; } v; v.f = f;
  uint32_t r = v.u + 0x7fffu + ((v.u >> 16) & 1u);
  return (u16)(r >> 16);
}
static __device__ __forceinline__ float rcp_f(float x){
  return __builtin_amdgcn_rcpf(x);   // 1-ulp approx: removes precise-div sequences
}
static __device__ __forceinline__ float sigmoid_f(float x){
  return rcp_f(1.f + __expf(-x));
}
static __device__ __forceinline__ float tanh_f(float x){
  x = fminf(15.f, fmaxf(-15.f, x));
  float e = __expf(2.f * x);
  return 1.f - 2.f * rcp_f(e + 1.f);
}

// ---------------- K0: weight transpose/convert ----------------
// WhT [n 1024][k 256] bf16; WxT/Wef hi/lo planes; WhS: kq 5,6,7 fragments
// restaged lane-contiguous: [w 4][ct 4][gt 4][kqm 3][lane 64][8 u16]
__global__ void k_prep(const float* __restrict__ Wh, const float* __restrict__ Wx,
                       const float* __restrict__ Wef1, const float* __restrict__ Wef3,
                       u16* __restrict__ WhT,
                       u16* __restrict__ WxTh, u16* __restrict__ WxTl,
                       u16* __restrict__ Wef1h, u16* __restrict__ Wef1l,
                       u16* __restrict__ Wef3h, u16* __restrict__ Wef3l,
                       u16* __restrict__ WhS){
  int idx = blockIdx.x*256 + threadIdx.x;
  if (idx < 262144){ int n = idx>>8, k = idx&255; WhT[idx] = f2bf(Wh[k*1024+n]); return; }
  idx -= 262144;
  if (idx < 131072){
    int n = idx>>7, k = idx&127; float w = Wx[k*1024+n];
    u16 h = f2bf(w); WxTh[idx] = h; WxTl[idx] = f2bf(w - bf2f(h)); return;
  }
  idx -= 131072;
  if (idx < 16384){
    int n = idx>>7, k = idx&127; float w = Wef1[k*128+n];
    u16 h = f2bf(w); Wef1h[idx] = h; Wef1l[idx] = f2bf(w - bf2f(h)); return;
  }
  idx -= 16384;
  if (idx < 32768){
    int n = idx>>7, k = idx&127; float w = Wef3[k*256+n];
    u16 h = f2bf(w); Wef3h[idx] = h; Wef3l[idx] = f2bf(w - bf2f(h)); return;
  }
  idx -= 32768;
  if (idx < 98304){
    int e = idx & 7, li = (idx >> 3) & 63, f = idx >> 9;   // f in [0,192)
    int w = f / 48, rem = f - w*48;
    int ct = rem / 12, rem2 = rem - ct*12;
    int gt = rem2 / 3, kqm = rem2 - gt*3;
    int n = gt*256 + w*64 + ct*16 + (li & 15);
    int k = (5 + kqm)*32 + (li >> 4)*8 + e;
    WhS[idx] = f2bf(Wh[k*1024 + n]);
    return;
  }
}

// ---------------- K1: embedding (chunked): rows m = sc*64 + b, hi/lo outputs ----------------
__global__ __launch_bounds__(256) void k_embed(
    const float* __restrict__ event, const float* __restrict__ vc, const float* __restrict__ vn,
    const float* __restrict__ Ve, const float* __restrict__ Vc, const float* __restrict__ Vn,
    u16* __restrict__ sHi, u16* __restrict__ sLo,
    u16* __restrict__ xHi, u16* __restrict__ xLo, int c0){
  __shared__ float VeL[64*128];
  __shared__ float VcL[32*128];
  __shared__ float VnL[16*128];
  __shared__ float evL[16*64];
  __shared__ float vcL[16*32];
  __shared__ float vnL[16*16];
  const int tid = threadIdx.x;
  const int sc = blockIdx.x >> 2;
  const int b0 = (blockIdx.x & 3) * 16;
  const int ss = c0 + sc;
  for (int i = tid; i < 64*128; i += 256) VeL[i] = Ve[i];
  for (int i = tid; i < 32*128; i += 256) VcL[i] = Vc[i];
  for (int i = tid; i < 16*128; i += 256) VnL[i] = Vn[i];
  for (int i = tid; i < 16*64; i += 256)
    evL[i] = event[((size_t)(b0 + (i>>6))*4096 + ss)*64 + (i&63)];
  for (int i = tid; i < 16*32; i += 256)
    vcL[i] = vc[((size_t)(b0 + (i>>5))*4096 + ss)*32 + (i&31)];
  for (int i = tid; i < 16*16; i += 256)
    vnL[i] = vn[((size_t)(b0 + (i>>4))*4096 + ss)*16 + (i&15)];
  __syncthreads();
  const int n = tid & 127, half = tid >> 7;
  for (int r = half; r < 16; r += 2){
    float sd = 0.f, cd = 0.f, nd = 0.f;
    #pragma unroll 8
    for (int k = 0; k < 64; ++k) sd = fmaf(evL[r*64+k], VeL[k*128+n], sd);
    #pragma unroll 8
    for (int k = 0; k < 32; ++k) cd = fmaf(vcL[r*32+k], VcL[k*128+n], cd);
    #pragma unroll 8
    for (int k = 0; k < 16; ++k) nd = fmaf(vnL[r*16+k], VnL[k*128+n], nd);
    float x = sd + 2.f*(cd + tanh_f(nd));
    size_t o = ((size_t)sc*64 + b0 + r)*128 + n;
    u16 sh = f2bf(sd); sHi[o] = sh; sLo[o] = f2bf(sd - bf2f(sh));
    u16 xh = f2bf(x);  xHi[o] = xh; xLo[o] = f2bf(x  - bf2f(xh));
  }
}

// ---------------- K2: split-bf16 ("bf16x3") MFMA GEMM, K=128, act+bias epilogue ----------------
// OUTKIND 0: f32 C[m][N]   1: f32 xw gate-interleaved [m][hid][gate]   2: hi/lo bf16 planes [m][N]
template<int ACT, int OUTKIND, int NTILES>
__global__ __launch_bounds__(256) void k_gemm(
    const u16* __restrict__ Ahi, const u16* __restrict__ Alo,
    const u16* __restrict__ BTh, const u16* __restrict__ BTl,
    const float* __restrict__ bias,
    float* __restrict__ CoutF, u16* __restrict__ CoutHi, u16* __restrict__ CoutLo){
  __shared__ u16 aLh[4][16*136];
  __shared__ u16 aLl[4][16*136];
  const int tid = threadIdx.x, lane = tid & 63, w = tid >> 6;
  const int c15 = lane & 15, q4 = lane >> 4;
  const size_t mbase = (size_t)blockIdx.x*64 + (size_t)w*16;
  const u16* Aph = Ahi + mbase*128;
  const u16* Apl = Alo + mbase*128;
  #pragma unroll
  for (int i = 0; i < 4; ++i){
    int row = q4 + i*4;
    *(bf16x8*)(&aLh[w][row*136 + c15*8]) = *(const bf16x8*)(Aph + row*128 + c15*8);
    *(bf16x8*)(&aLl[w][row*136 + c15*8]) = *(const bf16x8*)(Apl + row*128 + c15*8);
  }
  __syncthreads();
  bf16x8 ah[4], al[4];
  #pragma unroll
  for (int q = 0; q < 4; ++q){
    ah[q] = *(const bf16x8*)(&aLh[w][c15*136 + q*32 + q4*8]);
    al[q] = *(const bf16x8*)(&aLl[w][c15*136 + q*32 + q4*8]);
  }
  const u16* Bph = BTh + c15*128 + q4*8;
  const u16* Bpl = BTl + c15*128 + q4*8;

  bf16x8 bh[4], bl[4], bhn[4], bln[4];
  #pragma unroll
  for (int q = 0; q < 4; ++q){ bh[q] = *(const bf16x8*)(Bph + q*32); bl[q] = *(const bf16x8*)(Bpl + q*32); }

  for (int nt = 0; nt < NTILES; ++nt){
    if (nt + 1 < NTILES){
      #pragma unroll
      for (int q = 0; q < 4; ++q){
        bhn[q] = *(const bf16x8*)(Bph + (nt+1)*2048 + q*32);
        bln[q] = *(const bf16x8*)(Bpl + (nt+1)*2048 + q*32);
      }
    }
    f32x4 acc = (f32x4){0.f,0.f,0.f,0.f};
    #pragma unroll
    for (int q = 0; q < 4; ++q){
      acc = __builtin_amdgcn_mfma_f32_16x16x32_bf16(al[q], bh[q], acc, 0, 0, 0);
      acc = __builtin_amdgcn_mfma_f32_16x16x32_bf16(ah[q], bl[q], acc, 0, 0, 0);
      acc = __builtin_amdgcn_mfma_f32_16x16x32_bf16(ah[q], bh[q], acc, 0, 0, 0);
    }
    const int n = nt*16 + c15;
    const float bv = bias[n];
    #pragma unroll
    for (int i = 0; i < 4; ++i){
      float v = acc[i] + bv;
      if (ACT == 1) v = tanh_f(v);
      else if (ACT == 2) v = sigmoid_f(v);
      const size_t m = mbase + q4*4 + i;
      if (OUTKIND == 0){
        CoutF[m*(size_t)(NTILES*16) + n] = v;
      } else if (OUTKIND == 1){
        CoutF[m*1024 + (size_t)(n & 255)*4 + (size_t)(n >> 8)] = v;
      } else {
        size_t o = m*(size_t)(NTILES*16) + n;
        u16 hh = f2bf(v); CoutHi[o] = hh; CoutLo[o] = f2bf(v - bf2f(hh));
      }
    }
    #pragma unroll
    for (int q = 0; q < 4; ++q){ bh[q] = bhn[q]; bl[q] = bln[q]; }
  }
}

// ---------------- K3: the scan — ONE WG PER GROUP, zero cross-WG exchange ----------------
// 4 WGs (g = blockIdx), 256 threads, 4 waves at 1 wave/SIMD (512-VGPR budget).
// Wh residency is 3-tiered per wave: kq0-4 in registers (80 frags, 320 VGPR),
// kq5-6 in LDS (32 frags = 32KB/wave, preloaded once per chunk), kq7 streamed
// per step from the restaged L2-hot WhS (coalesced 16B/lane).
// h lives in a 16KB LDS double buffer in MFMA-A-fragment layout (bijective:
// frag kq = col>>5, lane = row + 16*((col&31)>>3), elem = col&7) — reads are
// lane-contiguous ds_read_b128, conflict-free. The per-step exchange is ONE
// __syncthreads (~100cy) instead of a ~2.5us MALL hop (rounds 0-6 showed the
// MALL protocol floor cannot be beaten from HIP source).
__global__ __launch_bounds__(256, 1) void k_scan(
    const u16* __restrict__ WhT, const u16* __restrict__ WhS,
    const float* __restrict__ xwG, const float* __restrict__ jG,
    const float* __restrict__ Wc, const float* __restrict__ h0, const float* __restrict__ c0in,
    const float* __restrict__ Wlin, const float* __restrict__ blin,
    float* __restrict__ stateF, float* __restrict__ out, int T0, int SC, int FINAL)
{
  __shared__ __align__(16) u16 BfLs[4][32][512];   // 128 KB: [w][frag][lane*8]
  __shared__ __align__(16) u16 hbufs[2][8][512];   // 16 KB: [buf][kq][lane*8]
  const int g = blockIdx.x;
  const int tid = threadIdx.x, lane = tid & 63, w = tid >> 6;
  const int c15 = lane & 15, q4 = lane >> 4;
  const int FIRST = (T0 == 0);

  // register B fragments: kq 0..4 (80 x bf16x8 = 320 VGPR)
  bf16x8 BfR[4][4][5];
  #pragma unroll
  for (int ct = 0; ct < 4; ++ct)
    #pragma unroll
    for (int gt = 0; gt < 4; ++gt){
      const u16* bp = WhT + (size_t)(gt*256 + w*64 + ct*16 + c15)*256 + q4*8;
      #pragma unroll
      for (int kq = 0; kq < 5; ++kq)
        BfR[ct][gt][kq] = *(const bf16x8*)(bp + kq*32);
    }

  // LDS B fragments: kq 5,6 (32/wave), from coalesced WhS staging
  #pragma unroll
  for (int fi = 0; fi < 32; ++fi){
    const int ct = fi >> 3, gt = (fi >> 1) & 3, kqm = fi & 1;
    bf16x8 v = *(const bf16x8*)(WhS + (size_t)(w*48 + ct*12 + gt*3 + kqm)*512 + lane*8);
    *(bf16x8*)(&BfLs[w][fi][lane*8]) = v;
  }

  // state + seed h fragments (buffer 0)
  float creg[4][4], hreg[4][4];
  float wcv[3][4];
  #pragma unroll
  for (int ct = 0; ct < 4; ++ct){
    const int col = w*64 + ct*16 + c15;
    wcv[0][ct] = Wc[col]; wcv[1][ct] = Wc[256+col]; wcv[2][ct] = Wc[512+col];
    #pragma unroll
    for (int i = 0; i < 4; ++i){
      const size_t r = (size_t)(g*16 + q4*4 + i);
      if (FIRST){ creg[ct][i] = c0in[r*256+col]; hreg[ct][i] = h0[r*256+col]; }
      else      { creg[ct][i] = stateF[r*256+col]; hreg[ct][i] = stateF[16384 + r*256+col]; }
      const int kqp = w*2 + (ct>>1);
      const int lp  = (q4*4+i) + 16*((ct&1)*2 + (c15>>3));
      hbufs[0][kqp][lp*8 + (c15&7)] = f2bf(hreg[ct][i]);
    }
  }
  __syncthreads();

  for (int t = 0; t < SC; ++t){
    const int rb = t & 1, wb = rb ^ 1;
    // A fragments (full h_t) from LDS: 8 conflict-free ds_read_b128
    bf16x8 A[8];
    #pragma unroll
    for (int kq = 0; kq < 8; ++kq)
      A[kq] = *(const bf16x8*)(&hbufs[rb][kq][lane*8]);
    const size_t mbase = (size_t)t*64 + g*16 + q4*4;

    #pragma unroll
    for (int ct = 0; ct < 4; ++ct){
      const int col = w*64 + ct*16 + c15;
      // xw/j prefetch for this ct (hides under the MFMA chain)
      f32x4 xq[4]; float jv[4];
      #pragma unroll
      for (int i = 0; i < 4; ++i){
        xq[i] = *(const f32x4*)(xwG + ((mbase+i)*1024 + (size_t)col*4));
        jv[i] = jG[(mbase+i)*256 + col];
      }
      f32x4 acc[4];
      #pragma unroll
      for (int gt = 0; gt < 4; ++gt) acc[gt] = (f32x4){0.f,0.f,0.f,0.f};

      // per-gt pipelined B loads (kq5,6 LDS; kq7 global) + MFMA chain kq 0..7
      bf16x8 nL0 = *(const bf16x8*)(&BfLs[w][ct*8 + 0][lane*8]);
      bf16x8 nL1 = *(const bf16x8*)(&BfLs[w][ct*8 + 1][lane*8]);
      bf16x8 nG  = *(const bf16x8*)(WhS + (size_t)(w*48 + ct*12 + 2)*512 + lane*8);
      #pragma unroll
      for (int gt = 0; gt < 4; ++gt){
        bf16x8 cL0 = nL0, cL1 = nL1, cG = nG;
        if (gt < 3){
          nL0 = *(const bf16x8*)(&BfLs[w][ct*8 + (gt+1)*2 + 0][lane*8]);
          nL1 = *(const bf16x8*)(&BfLs[w][ct*8 + (gt+1)*2 + 1][lane*8]);
          nG  = *(const bf16x8*)(WhS + (size_t)(w*48 + ct*12 + (gt+1)*3 + 2)*512 + lane*8);
        }
        #pragma unroll
        for (int kq = 0; kq < 5; ++kq)
          acc[gt] = __builtin_amdgcn_mfma_f32_16x16x32_bf16(A[kq], BfR[ct][gt][kq], acc[gt], 0, 0, 0);
        acc[gt] = __builtin_amdgcn_mfma_f32_16x16x32_bf16(A[5], cL0, acc[gt], 0, 0, 0);
        acc[gt] = __builtin_amdgcn_mfma_f32_16x16x32_bf16(A[6], cL1, acc[gt], 0, 0, 0);
        acc[gt] = __builtin_amdgcn_mfma_f32_16x16x32_bf16(A[7], cG,  acc[gt], 0, 0, 0);
      }

      const int kqp = w*2 + (ct>>1);
      #pragma unroll
      for (int i = 0; i < 4; ++i){
        float ip = acc[0][i] + xq[i][0] + creg[ct][i]*wcv[0][ct];
        float fp = acc[1][i] + xq[i][1] + creg[ct][i]*wcv[1][ct];
        float gp = acc[2][i] + xq[i][2];
        float op = acc[3][i] + xq[i][3] + creg[ct][i]*wcv[2][ct];
        float it2 = sigmoid_f(ip);
        float ft  = sigmoid_f(fp);
        float gtv = tanh_f(gp);
        float ot  = sigmoid_f(op);
        float chat = ft*creg[ct][i] + it2*gtv;
        float cn = creg[ct][i] + jv[i]*(chat - creg[ct][i]);
        float hhat = ot*tanh_f(chat);
        float hn = hreg[ct][i] + jv[i]*(hhat - hreg[ct][i]);
        creg[ct][i] = cn; hreg[ct][i] = hn;
        const int lp = (q4*4+i) + 16*((ct&1)*2 + (c15>>3));
        hbufs[wb][kqp][lp*8 + (c15&7)] = f2bf(hn);
      }
    }
    __syncthreads();   // next step's A reads see all waves' h writes
  }

  // persist f32 state for next chunk
  if (!FINAL){
    #pragma unroll
    for (int ct = 0; ct < 4; ++ct){
      const int col = w*64 + ct*16 + c15;
      #pragma unroll
      for (int i = 0; i < 4; ++i){
        const size_t r = (size_t)(g*16 + q4*4 + i);
        stateF[r*256 + col] = creg[ct][i];
        stateF[16384 + r*256 + col] = hreg[ct][i];
      }
    }
  }

  // epilogue on final chunk: out = h_T @ Wlin + blin (h_T in hbufs[0]; SC even)
  if (FINAL){
    float* hF = (float*)&BfLs[0][0][0];   // BfLs dead: reuse 16 KB
    for (int idx = tid; idx < 4096; idx += 256){
      const int r = idx >> 8, c = idx & 255;
      const int fq = c >> 5, k32 = c & 31;
      const int lp = r + 16*(k32 >> 3), e = k32 & 7;
      hF[r*256 + c] = bf2f(hbufs[0][fq][lp*8 + e]);
    }
    __syncthreads();
    for (int idx = tid; idx < 1024; idx += 256){
      const int r = idx >> 6, dcol = idx & 63;
      float aacc = blin[dcol];
      for (int k = 0; k < 256; ++k)
        aacc = fmaf(hF[r*256 + k], Wlin[k*64 + dcol], aacc);
      out[(size_t)(g*16 + r)*64 + dcol] = aacc;
    }
  }
}

// ---------------- host ----------------
extern "C" void kernel_launch(void* const* d_in, const int* in_sizes, int n_in,
                              void* d_out, int out_size, void* d_ws, size_t ws_size,
                              hipStream_t stream)
{
  (void)in_sizes; (void)n_in;
  const float* event = (const float*)d_in[0];
  const float* vc    = (const float*)d_in[2];
  const float* vn    = (const float*)d_in[3];
  const float* h0    = (const float*)d_in[4];
  const float* c0v   = (const float*)d_in[5];
  const float* Wx    = (const float*)d_in[6];
  const float* Wh    = (const float*)d_in[7];
  const float* Wc    = (const float*)d_in[8];
  const float* bias  = (const float*)d_in[9];
  const float* Ve    = (const float*)d_in[10];
  const float* Vc    = (const float*)d_in[11];
  const float* Vn    = (const float*)d_in[12];
  const float* Wlin  = (const float*)d_in[13];
  const float* blin  = (const float*)d_in[14];
  const float* Wef1  = (const float*)d_in[15];
  const float* bef1  = (const float*)d_in[16];
  const float* Wef3  = (const float*)d_in[17];
  const float* bef3  = (const float*)d_in[18];

  int SC = 0;
  const int cands[9] = {4096, 2048, 1024, 512, 256, 128, 64, 32, 16};
  for (int i = 0; i < 9; ++i){
    if (OFF_CH + (size_t)cands[i]*CH_BYTES_PER_SC <= ws_size){ SC = cands[i]; break; }
  }
  if (SC == 0){
    hipMemsetAsync(d_out, 0, (size_t)out_size*sizeof(float), stream);
    return;
  }
  const int C = NS / SC;

  char* ws = (char*)d_ws;
  u16*   WhS    = (u16*)(ws + OFF_WHS);
  float* stateF = (float*)(ws + OFF_STATE);
  u16* WhT   = (u16*)(ws + OFF_WHT);
  u16* WxTh  = (u16*)(ws + OFF_WXTH);
  u16* WxTl  = (u16*)(ws + OFF_WXTL);
  u16* Wef1h = (u16*)(ws + OFF_WEF1H);
  u16* Wef1l = (u16*)(ws + OFF_WEF1L);
  u16* Wef3h = (u16*)(ws + OFF_WEF3H);
  u16* Wef3l = (u16*)(ws + OFF_WEF3L);
  char* ch = ws + OFF_CH;
  u16* sHi  = (u16*)ch;
  u16* sLo  = (u16*)(ch + (size_t)SC*16384);
  u16* xHi  = (u16*)(ch + (size_t)SC*32768);
  u16* xLo  = (u16*)(ch + (size_t)SC*49152);
  u16* e1Hi = (u16*)(ch + (size_t)SC*65536);
  u16* e1Lo = (u16*)(ch + (size_t)SC*81920);
  float* xwG = (float*)(ch + (size_t)SC*98304);
  float* jG  = (float*)(ch + (size_t)SC*360448);

  k_prep<<<2112, 256, 0, stream>>>(Wh, Wx, Wef1, Wef3, WhT, WxTh, WxTl,
                                   Wef1h, Wef1l, Wef3h, Wef3l, WhS);

  for (int c = 0; c < C; ++c){
    const int c0 = c * SC;
    k_embed<<<SC*4, 256, 0, stream>>>(event, vc, vn, Ve, Vc, Vn, sHi, sLo, xHi, xLo, c0);
    k_gemm<0,1,64><<<SC, 256, 0, stream>>>(xHi, xLo, WxTh, WxTl, bias, xwG, nullptr, nullptr);
    k_gemm<1,2,8><<<SC, 256, 0, stream>>>(sHi, sLo, Wef1h, Wef1l, bef1, nullptr, e1Hi, e1Lo);
    k_gemm<2,0,16><<<SC, 256, 0, stream>>>(e1Hi, e1Lo, Wef3h, Wef3l, bef3, jG, nullptr, nullptr);
    k_scan<<<4, 256, 0, stream>>>(WhT, WhS, xwG, jG, Wc, h0, c0v, Wlin, blin,
                                  stateF, (float*)d_out, c0, SC, (c == C-1) ? 1 : 0);
  }
}